// Round 1
// baseline (1238.891 us; speedup 1.0000x reference)
//
#include <hip/hip_runtime.h>
#include <hip/hip_bf16.h>
#include <math.h>

#define NN 100000
#define EE 1000000
#define GG 64
#define BN_EPS 1e-5f

// ---------------- degree count ----------------
__global__ __launch_bounds__(256) void k_count(const int* __restrict__ dst,
                                               int* __restrict__ cnt, int E) {
  int i = blockIdx.x * 256 + threadIdx.x;
  if (i < E) atomicAdd(&cnt[dst[i]], 1);
}

__global__ __launch_bounds__(256) void k_dinv(const int* __restrict__ cnt,
                                              float* __restrict__ dinv, int N) {
  int i = blockIdx.x * 256 + threadIdx.x;
  if (i < N) dinv[i] = rsqrtf(1.0f + (float)cnt[i]);
}

// single-block exclusive scan over cnt -> rowstart (N+1), cursor copy
__global__ __launch_bounds__(1024) void k_scan(const int* __restrict__ cnt,
                                               int* __restrict__ rowstart,
                                               int* __restrict__ cursor, int N) {
  __shared__ int part[1024];
  int tid = threadIdx.x;
  int per = (N + 1023) >> 10;
  int b = tid * per;
  int e = min(b + per, N);
  int s = 0;
  for (int i = b; i < e; ++i) s += cnt[i];
  part[tid] = s;
  __syncthreads();
  for (int off = 1; off < 1024; off <<= 1) {
    int v = (tid >= off) ? part[tid - off] : 0;
    __syncthreads();
    part[tid] += v;
    __syncthreads();
  }
  int run = (tid > 0) ? part[tid - 1] : 0;
  for (int i = b; i < e; ++i) {
    rowstart[i] = run;
    cursor[i] = run;
    run += cnt[i];
  }
  if (tid == 1023) rowstart[N] = run;
}

__global__ __launch_bounds__(256) void k_fill(const int* __restrict__ src,
                                              const int* __restrict__ dst,
                                              int* __restrict__ cursor,
                                              int* __restrict__ eidx, int E) {
  int i = blockIdx.x * 256 + threadIdx.x;
  if (i < E) {
    int pos = atomicAdd(&cursor[dst[i]], 1);
    eidx[pos] = src[i];
  }
}

// ---------------- GEMM: Y[N,M] = f(X)[N,K] @ W[K,M] ----------------
// BN: apply batchnorm+relu to X elements while staging to LDS.
// OBR: apply (+obias, relu) to output.
template <int K, int M, int BN, int OBR>
__global__ __launch_bounds__(256) void k_gemm(
    const float* __restrict__ X, const float* __restrict__ W,
    const float* __restrict__ bn_mean, const float* __restrict__ bn_var,
    const float* __restrict__ bn_g, const float* __restrict__ bn_b,
    const float* __restrict__ obias, float* __restrict__ Y, int nrows) {
  constexpr int ROWS = 64;
  constexpr int KC = (K > 64) ? 64 : K;  // K-chunk so LDS <= 64KB
  constexpr int CG = M / 4;              // column groups (4 cols each)
  constexpr int RG = 256 / CG;           // row groups
  constexpr int RPG = ROWS / RG;         // rows per thread
  __shared__ float Xs[ROWS * K];
  __shared__ float Ws[KC * M];
  const int tid = threadIdx.x;
  const int row0 = blockIdx.x * ROWS;

  // stage X tile (with optional fused BN+relu)
  constexpr int XV = ROWS * K / 4;
  for (int i = tid; i < XV; i += 256) {
    int flat = i * 4;
    int r = flat / K, k = flat % K;
    int row = row0 + r;
    float4 v = make_float4(0.f, 0.f, 0.f, 0.f);
    if (row < nrows) v = *(const float4*)(X + (size_t)row * K + k);
    if constexpr (BN) {
      float4 mn = *(const float4*)(bn_mean + k);
      float4 vr = *(const float4*)(bn_var + k);
      float4 gm = *(const float4*)(bn_g + k);
      float4 bt = *(const float4*)(bn_b + k);
      v.x = fmaxf((v.x - mn.x) * rsqrtf(vr.x + BN_EPS) * gm.x + bt.x, 0.f);
      v.y = fmaxf((v.y - mn.y) * rsqrtf(vr.y + BN_EPS) * gm.y + bt.y, 0.f);
      v.z = fmaxf((v.z - mn.z) * rsqrtf(vr.z + BN_EPS) * gm.z + bt.z, 0.f);
      v.w = fmaxf((v.w - mn.w) * rsqrtf(vr.w + BN_EPS) * gm.w + bt.w, 0.f);
    }
    *(float4*)(Xs + flat) = v;
  }

  const int c4 = (tid % CG) * 4;
  const int rg = tid / CG;
  float4 acc[RPG];
#pragma unroll
  for (int r = 0; r < RPG; ++r) acc[r] = make_float4(0.f, 0.f, 0.f, 0.f);

  for (int kc = 0; kc < K; kc += KC) {
    __syncthreads();
    for (int i = tid; i < KC * M / 4; i += 256)
      *(float4*)(Ws + i * 4) = *(const float4*)(W + (size_t)kc * M + i * 4);
    __syncthreads();
#pragma unroll 4
    for (int kk = 0; kk < KC; kk += 4) {
      float4 w0 = *(const float4*)(Ws + (kk + 0) * M + c4);
      float4 w1 = *(const float4*)(Ws + (kk + 1) * M + c4);
      float4 w2 = *(const float4*)(Ws + (kk + 2) * M + c4);
      float4 w3 = *(const float4*)(Ws + (kk + 3) * M + c4);
#pragma unroll
      for (int r = 0; r < RPG; ++r) {
        float4 xv = *(const float4*)(Xs + (rg * RPG + r) * K + kc + kk);
        acc[r].x += xv.x * w0.x + xv.y * w1.x + xv.z * w2.x + xv.w * w3.x;
        acc[r].y += xv.x * w0.y + xv.y * w1.y + xv.z * w2.y + xv.w * w3.y;
        acc[r].z += xv.x * w0.z + xv.y * w1.z + xv.z * w2.z + xv.w * w3.z;
        acc[r].w += xv.x * w0.w + xv.y * w1.w + xv.z * w2.w + xv.w * w3.w;
      }
    }
  }

#pragma unroll
  for (int r = 0; r < RPG; ++r) {
    int row = row0 + rg * RPG + r;
    if (row < nrows) {
      float4 v = acc[r];
      if constexpr (OBR) {
        float4 ob = *(const float4*)(obias + c4);
        v.x = fmaxf(v.x + ob.x, 0.f);
        v.y = fmaxf(v.y + ob.y, 0.f);
        v.z = fmaxf(v.z + ob.z, 0.f);
        v.w = fmaxf(v.w + ob.w, 0.f);
      }
      *(float4*)(Y + (size_t)row * M + c4) = v;
    }
  }
}

// ---------------- GCN aggregation (gather over CSR by dst) ----------------
// out[n] = sum_{e: dst=n} h[src_e]*dinv[src_e]*dinv[n] + h[n]*dinv[n]^2 + bias
template <int M>
__global__ __launch_bounds__(256) void k_agg(const float* __restrict__ h,
                                             const int* __restrict__ rowstart,
                                             const int* __restrict__ eidx,
                                             const float* __restrict__ dinv,
                                             const float* __restrict__ bias,
                                             float* __restrict__ out, int N) {
  int w = (blockIdx.x * 256 + threadIdx.x) >> 6;  // wave = node
  int l = threadIdx.x & 63;
  if (w >= N) return;
  float di = dinv[w];
  int lo = rowstart[w], hi = rowstart[w + 1];
  if constexpr (M == 128) {
    float2 self = ((const float2*)(h + (size_t)w * 128))[l];
    float2 bb = ((const float2*)bias)[l];
    float sc = di * di;
    float2 acc;
    acc.x = self.x * sc + bb.x;
    acc.y = self.y * sc + bb.y;
    for (int e = lo; e < hi; ++e) {
      int s = eidx[e];
      float nr = dinv[s] * di;
      float2 v = ((const float2*)(h + (size_t)s * 128))[l];
      acc.x += v.x * nr;
      acc.y += v.y * nr;
    }
    ((float2*)(out + (size_t)w * 128))[l] = acc;
  } else {
    float acc = h[(size_t)w * 64 + l] * di * di + bias[l];
    for (int e = lo; e < hi; ++e) {
      int s = eidx[e];
      acc += h[(size_t)s * 64 + l] * (dinv[s] * di);
    }
    out[(size_t)w * 64 + l] = acc;
  }
}

// ---------------- gate = t1 @ Wg2 + bg2 (wave-per-node dot) ----------------
__global__ __launch_bounds__(256) void k_gatedot(const float* __restrict__ t1,
                                                 const float* __restrict__ Wg2,
                                                 const float* __restrict__ bg2,
                                                 float* __restrict__ gate, int N) {
  int w = (blockIdx.x * 256 + threadIdx.x) >> 6;
  int l = threadIdx.x & 63;
  if (w >= N) return;
  float2 v = ((const float2*)(t1 + (size_t)w * 128))[l];
  float2 g2 = ((const float2*)Wg2)[l];
  float p = v.x * g2.x + v.y * g2.y;
  for (int off = 32; off; off >>= 1) p += __shfl_down(p, off, 64);
  if (l == 0) gate[w] = p + bg2[0];
}

// ---------------- softmax pooling (block per graph) ----------------
__device__ inline int lower_bound_i(const int* a, int n, int v) {
  int lo = 0, hi = n;
  while (lo < hi) {
    int mid = (lo + hi) >> 1;
    if (a[mid] < v) lo = mid + 1;
    else hi = mid;
  }
  return lo;
}

__global__ __launch_bounds__(256) void k_pool(const float* __restrict__ gate,
                                              const int* __restrict__ batch,
                                              const float* __restrict__ h3,
                                              float* __restrict__ pooled, int N) {
  __shared__ float red[256];
  __shared__ int sb[2];
  __shared__ float sm[2];
  int g = blockIdx.x, tid = threadIdx.x;
  if (tid == 0) {
    sb[0] = lower_bound_i(batch, N, g);
    sb[1] = lower_bound_i(batch, N, g + 1);
  }
  __syncthreads();
  int lo = sb[0], hi = sb[1];
  // max
  float mx = -INFINITY;
  for (int i = lo + tid; i < hi; i += 256) mx = fmaxf(mx, gate[i]);
  red[tid] = mx;
  __syncthreads();
  for (int o = 128; o; o >>= 1) {
    if (tid < o) red[tid] = fmaxf(red[tid], red[tid + o]);
    __syncthreads();
  }
  if (tid == 0) sm[0] = red[0];
  __syncthreads();
  float m = sm[0];
  // sum of exp
  float s = 0.f;
  for (int i = lo + tid; i < hi; i += 256) s += expf(gate[i] - m);
  red[tid] = s;
  __syncthreads();
  for (int o = 128; o; o >>= 1) {
    if (tid < o) red[tid] += red[tid + o];
    __syncthreads();
  }
  if (tid == 0) sm[1] = (red[0] > 0.f) ? 1.0f / red[0] : 0.f;
  __syncthreads();
  float inv = sm[1];
  // weighted feature sum
  int d = tid & 63, sub = tid >> 6;
  float acc = 0.f;
  for (int i = lo + sub; i < hi; i += 4)
    acc += h3[(size_t)i * 64 + d] * expf(gate[i] - m);
  red[tid] = acc;
  __syncthreads();
  if (tid < 64)
    pooled[g * 64 + tid] =
        (red[tid] + red[tid + 64] + red[tid + 128] + red[tid + 192]) * inv;
}

// ---------------- head MLP (single block) ----------------
__global__ __launch_bounds__(256) void k_head(const float* __restrict__ pooled,
                                              const float* __restrict__ Wm1,
                                              const float* __restrict__ bm1,
                                              const float* __restrict__ Wm2,
                                              const float* __restrict__ bm2,
                                              float* __restrict__ out) {
  __shared__ float P[64 * 64];
  __shared__ float T[64 * 128];
  int tid = threadIdx.x;
  for (int i = tid; i < 4096; i += 256) P[i] = pooled[i];
  __syncthreads();
  for (int e = tid; e < 8192; e += 256) {
    int r = e >> 7, c = e & 127;
    float a = bm1[c];
    for (int k = 0; k < 64; ++k) a += P[r * 64 + k] * Wm1[k * 128 + c];
    T[e] = fmaxf(a, 0.f);
  }
  __syncthreads();
  for (int e = tid; e < 4096; e += 256) {
    int r = e >> 6, c = e & 63;
    float a = bm2[c];
    for (int k = 0; k < 128; ++k) a += T[r * 128 + k] * Wm2[k * 64 + c];
    out[e] = a;
  }
}

extern "C" void kernel_launch(void* const* d_in, const int* in_sizes, int n_in,
                              void* d_out, int out_size, void* d_ws,
                              size_t ws_size, hipStream_t stream) {
  const int N = NN, E = EE;
  const float* x = (const float*)d_in[0];
  const int* ei = (const int*)d_in[1];
  const int* batch = (const int*)d_in[2];
  const float* W1 = (const float*)d_in[3];
  const float* b1 = (const float*)d_in[4];
  const float* W2 = (const float*)d_in[5];
  const float* b2 = (const float*)d_in[6];
  const float* W3 = (const float*)d_in[7];
  const float* b3 = (const float*)d_in[8];
  const float* g1 = (const float*)d_in[9];
  const float* beta1 = (const float*)d_in[10];
  const float* g2 = (const float*)d_in[11];
  const float* beta2 = (const float*)d_in[12];
  const float* mean1 = (const float*)d_in[13];
  const float* var1 = (const float*)d_in[14];
  const float* mean2 = (const float*)d_in[15];
  const float* var2 = (const float*)d_in[16];
  const float* Wg1 = (const float*)d_in[17];
  const float* bg1 = (const float*)d_in[18];
  const float* Wg2 = (const float*)d_in[19];
  const float* bg2 = (const float*)d_in[20];
  const float* Wm1 = (const float*)d_in[21];
  const float* bm1 = (const float*)d_in[22];
  const float* Wm2 = (const float*)d_in[23];
  const float* bm2 = (const float*)d_in[24];
  float* out = (float*)d_out;

  const int* src = ei;
  const int* dst = ei + E;

  // workspace layout (all 16B aligned since N,E are multiples of 4)
  char* wsb = (char*)d_ws;
  size_t off = 0;
  auto alloc = [&](size_t elems) -> void* {
    void* p = wsb + off;
    off += elems * 4;
    return p;
  };
  int* cnt = (int*)alloc(N);
  int* rowstart = (int*)alloc(N + 4);
  int* cursor = (int*)alloc(N);
  int* eidx = (int*)alloc(E);
  float* dinv = (float*)alloc(N);
  float* gate = (float*)alloc(N);
  float* bufA = (float*)alloc((size_t)N * 128);
  float* bufB = (float*)alloc((size_t)N * 128);
  float* pooled = (float*)alloc(64 * 64);
  (void)ws_size;
  (void)n_in;
  (void)in_sizes;
  (void)out_size;

  // CSR build (once, reused for all 3 conv layers)
  hipMemsetAsync(cnt, 0, N * sizeof(int), stream);
  k_count<<<(E + 255) / 256, 256, 0, stream>>>(dst, cnt, E);
  k_dinv<<<(N + 255) / 256, 256, 0, stream>>>(cnt, dinv, N);
  k_scan<<<1, 1024, 0, stream>>>(cnt, rowstart, cursor, N);
  k_fill<<<(E + 255) / 256, 256, 0, stream>>>(src, dst, cursor, eidx, E);

  const int gb = (N + 63) / 64;         // GEMM blocks
  const int ab = (N * 64 + 255) / 256;  // agg/gatedot blocks (wave per node)

  // Layer 1: h = x@W1 ; agg ; (BN1+relu fused into next gemm's load)
  k_gemm<128, 128, 0, 0><<<gb, 256, 0, stream>>>(
      x, W1, nullptr, nullptr, nullptr, nullptr, nullptr, bufA, N);
  k_agg<128><<<ab, 256, 0, stream>>>(bufA, rowstart, eidx, dinv, b1, bufB, N);

  // Layer 2
  k_gemm<128, 128, 1, 0><<<gb, 256, 0, stream>>>(
      bufB, W2, mean1, var1, g1, beta1, nullptr, bufA, N);
  k_agg<128><<<ab, 256, 0, stream>>>(bufA, rowstart, eidx, dinv, b2, bufB, N);

  // Layer 3 (output dim 64)
  k_gemm<128, 64, 1, 0><<<gb, 256, 0, stream>>>(
      bufB, W3, mean2, var2, g2, beta2, nullptr, bufA, N);
  k_agg<64><<<ab, 256, 0, stream>>>(bufA, rowstart, eidx, dinv, b3, bufB, N);
  // h3 = bufB (N x 64)

  // gate MLP: t1 = relu(h3@Wg1+bg1) -> bufA ; gate = t1@Wg2+bg2
  k_gemm<64, 128, 0, 1><<<gb, 256, 0, stream>>>(
      bufB, Wg1, nullptr, nullptr, nullptr, nullptr, bg1, bufA, N);
  k_gatedot<<<ab, 256, 0, stream>>>(bufA, Wg2, bg2, gate, N);

  // softmax pooling per graph
  k_pool<<<GG, 256, 0, stream>>>(gate, batch, bufB, pooled, N);

  // head MLP
  k_head<<<1, 256, 0, stream>>>(pooled, Wm1, bm1, Wm2, bm2, out);
}

// Round 2
// 1010.778 us; speedup vs baseline: 1.2257x; 1.2257x over previous
//
#include <hip/hip_runtime.h>
#include <hip/hip_bf16.h>
#include <math.h>

#define NN 100000
#define EE 1000000
#define GG 64
#define BN_EPS 1e-5f
#define SB 512  // scan block size

// ---------------- degree count ----------------
__global__ __launch_bounds__(256) void k_count(const int* __restrict__ dst,
                                               int* __restrict__ cnt, int E) {
  int i = blockIdx.x * 256 + threadIdx.x;
  if (i < E) atomicAdd(&cnt[dst[i]], 1);
}

// ---------------- hierarchical scan ----------------
// phase 1: per-block reduce of cnt -> bsum ; fused dinv
__global__ __launch_bounds__(SB) void k_scan1(const int* __restrict__ cnt,
                                              float* __restrict__ dinv,
                                              int* __restrict__ bsum, int N) {
  __shared__ int red[SB];
  int t = threadIdx.x;
  int i = blockIdx.x * SB + t;
  int v = (i < N) ? cnt[i] : 0;
  if (i < N) dinv[i] = rsqrtf(1.0f + (float)v);
  red[t] = v;
  __syncthreads();
  for (int o = SB / 2; o; o >>= 1) {
    if (t < o) red[t] += red[t + o];
    __syncthreads();
  }
  if (t == 0) bsum[blockIdx.x] = red[0];
}

// phase 2: single small block scans the (<=256) block partials -> boff (exclusive)
__global__ __launch_bounds__(256) void k_scan2(const int* __restrict__ bsum,
                                               int* __restrict__ boff, int nb,
                                               int* __restrict__ total_out) {
  __shared__ int s[256];
  int t = threadIdx.x;
  int v = (t < nb) ? bsum[t] : 0;
  s[t] = v;
  __syncthreads();
  for (int o = 1; o < 256; o <<= 1) {
    int u = (t >= o) ? s[t - o] : 0;
    __syncthreads();
    s[t] += u;
    __syncthreads();
  }
  boff[t] = s[t] - v;  // exclusive
  if (t == 255) *total_out = s[255];
}

// phase 3: per-block exclusive scan + block offset -> rowstart, cursor
__global__ __launch_bounds__(SB) void k_scan3(const int* __restrict__ cnt,
                                              const int* __restrict__ boff,
                                              int* __restrict__ rowstart,
                                              int* __restrict__ cursor, int N) {
  __shared__ int s[SB];
  int t = threadIdx.x;
  int i = blockIdx.x * SB + t;
  int v = (i < N) ? cnt[i] : 0;
  s[t] = v;
  __syncthreads();
  for (int o = 1; o < SB; o <<= 1) {
    int u = (t >= o) ? s[t - o] : 0;
    __syncthreads();
    s[t] += u;
    __syncthreads();
  }
  int excl = s[t] - v + boff[blockIdx.x];
  if (i < N) {
    rowstart[i] = excl;
    cursor[i] = excl;
  }
}

__global__ __launch_bounds__(256) void k_fill(const int* __restrict__ src,
                                              const int* __restrict__ dst,
                                              int* __restrict__ cursor,
                                              int* __restrict__ eidx, int E) {
  int i = blockIdx.x * 256 + threadIdx.x;
  if (i < E) {
    int pos = atomicAdd(&cursor[dst[i]], 1);
    eidx[pos] = src[i];
  }
}

// ---------------- GEMM: Y[N,M] = f(X)[N,K] @ W[K,M] ----------------
// BN: apply batchnorm+relu to X elements while staging to LDS.
// OBR: apply (+obias, relu) to output.
template <int K, int M, int BN, int OBR>
__global__ __launch_bounds__(256) void k_gemm(
    const float* __restrict__ X, const float* __restrict__ W,
    const float* __restrict__ bn_mean, const float* __restrict__ bn_var,
    const float* __restrict__ bn_g, const float* __restrict__ bn_b,
    const float* __restrict__ obias, float* __restrict__ Y, int nrows) {
  constexpr int ROWS = 64;
  constexpr int KC = (K > 64) ? 64 : K;  // K-chunk so LDS <= 64KB
  constexpr int CG = M / 4;              // column groups (4 cols each)
  constexpr int RG = 256 / CG;           // row groups
  constexpr int RPG = ROWS / RG;         // rows per thread
  __shared__ float Xs[ROWS * K];
  __shared__ float Ws[KC * M];
  const int tid = threadIdx.x;
  const int row0 = blockIdx.x * ROWS;

  // stage X tile (with optional fused BN+relu)
  constexpr int XV = ROWS * K / 4;
  for (int i = tid; i < XV; i += 256) {
    int flat = i * 4;
    int r = flat / K, k = flat % K;
    int row = row0 + r;
    float4 v = make_float4(0.f, 0.f, 0.f, 0.f);
    if (row < nrows) v = *(const float4*)(X + (size_t)row * K + k);
    if constexpr (BN) {
      float4 mn = *(const float4*)(bn_mean + k);
      float4 vr = *(const float4*)(bn_var + k);
      float4 gm = *(const float4*)(bn_g + k);
      float4 bt = *(const float4*)(bn_b + k);
      v.x = fmaxf((v.x - mn.x) * rsqrtf(vr.x + BN_EPS) * gm.x + bt.x, 0.f);
      v.y = fmaxf((v.y - mn.y) * rsqrtf(vr.y + BN_EPS) * gm.y + bt.y, 0.f);
      v.z = fmaxf((v.z - mn.z) * rsqrtf(vr.z + BN_EPS) * gm.z + bt.z, 0.f);
      v.w = fmaxf((v.w - mn.w) * rsqrtf(vr.w + BN_EPS) * gm.w + bt.w, 0.f);
    }
    *(float4*)(Xs + flat) = v;
  }

  const int c4 = (tid % CG) * 4;
  const int rg = tid / CG;
  float4 acc[RPG];
#pragma unroll
  for (int r = 0; r < RPG; ++r) acc[r] = make_float4(0.f, 0.f, 0.f, 0.f);

  for (int kc = 0; kc < K; kc += KC) {
    __syncthreads();
    for (int i = tid; i < KC * M / 4; i += 256)
      *(float4*)(Ws + i * 4) = *(const float4*)(W + (size_t)kc * M + i * 4);
    __syncthreads();
#pragma unroll 4
    for (int kk = 0; kk < KC; kk += 4) {
      float4 w0 = *(const float4*)(Ws + (kk + 0) * M + c4);
      float4 w1 = *(const float4*)(Ws + (kk + 1) * M + c4);
      float4 w2 = *(const float4*)(Ws + (kk + 2) * M + c4);
      float4 w3 = *(const float4*)(Ws + (kk + 3) * M + c4);
#pragma unroll
      for (int r = 0; r < RPG; ++r) {
        float4 xv = *(const float4*)(Xs + (rg * RPG + r) * K + kc + kk);
        acc[r].x += xv.x * w0.x + xv.y * w1.x + xv.z * w2.x + xv.w * w3.x;
        acc[r].y += xv.x * w0.y + xv.y * w1.y + xv.z * w2.y + xv.w * w3.y;
        acc[r].z += xv.x * w0.z + xv.y * w1.z + xv.z * w2.z + xv.w * w3.z;
        acc[r].w += xv.x * w0.w + xv.y * w1.w + xv.z * w2.w + xv.w * w3.w;
      }
    }
  }

#pragma unroll
  for (int r = 0; r < RPG; ++r) {
    int row = row0 + rg * RPG + r;
    if (row < nrows) {
      float4 v = acc[r];
      if constexpr (OBR) {
        float4 ob = *(const float4*)(obias + c4);
        v.x = fmaxf(v.x + ob.x, 0.f);
        v.y = fmaxf(v.y + ob.y, 0.f);
        v.z = fmaxf(v.z + ob.z, 0.f);
        v.w = fmaxf(v.w + ob.w, 0.f);
      }
      *(float4*)(Y + (size_t)row * M + c4) = v;
    }
  }
}

// ---------------- GCN aggregation (gather over CSR by dst) ----------------
// out[n] = sum_{e: dst=n} h[src_e]*dinv[src_e]*dinv[n] + h[n]*dinv[n]^2 + bias
template <int M>
__global__ __launch_bounds__(256) void k_agg(const float* __restrict__ h,
                                             const int* __restrict__ rowstart,
                                             const int* __restrict__ eidx,
                                             const float* __restrict__ dinv,
                                             const float* __restrict__ bias,
                                             float* __restrict__ out, int N) {
  int w = (blockIdx.x * 256 + threadIdx.x) >> 6;  // wave = node
  int l = threadIdx.x & 63;
  if (w >= N) return;
  float di = dinv[w];
  int lo = rowstart[w], hi = rowstart[w + 1];
  if constexpr (M == 128) {
    float2 self = ((const float2*)(h + (size_t)w * 128))[l];
    float2 bb = ((const float2*)bias)[l];
    float sc = di * di;
    float2 acc;
    acc.x = self.x * sc + bb.x;
    acc.y = self.y * sc + bb.y;
    for (int e = lo; e < hi; ++e) {
      int s = eidx[e];
      float nr = dinv[s] * di;
      float2 v = ((const float2*)(h + (size_t)s * 128))[l];
      acc.x += v.x * nr;
      acc.y += v.y * nr;
    }
    ((float2*)(out + (size_t)w * 128))[l] = acc;
  } else {
    float acc = h[(size_t)w * 64 + l] * di * di + bias[l];
    for (int e = lo; e < hi; ++e) {
      int s = eidx[e];
      acc += h[(size_t)s * 64 + l] * (dinv[s] * di);
    }
    out[(size_t)w * 64 + l] = acc;
  }
}

// ---------------- gate = t1 @ Wg2 + bg2 (wave-per-node dot) ----------------
__global__ __launch_bounds__(256) void k_gatedot(const float* __restrict__ t1,
                                                 const float* __restrict__ Wg2,
                                                 const float* __restrict__ bg2,
                                                 float* __restrict__ gate, int N) {
  int w = (blockIdx.x * 256 + threadIdx.x) >> 6;
  int l = threadIdx.x & 63;
  if (w >= N) return;
  float2 v = ((const float2*)(t1 + (size_t)w * 128))[l];
  float2 g2 = ((const float2*)Wg2)[l];
  float p = v.x * g2.x + v.y * g2.y;
  for (int off = 32; off; off >>= 1) p += __shfl_down(p, off, 64);
  if (l == 0) gate[w] = p + bg2[0];
}

// ---------------- softmax pooling (block per graph) ----------------
__device__ inline int lower_bound_i(const int* a, int n, int v) {
  int lo = 0, hi = n;
  while (lo < hi) {
    int mid = (lo + hi) >> 1;
    if (a[mid] < v) lo = mid + 1;
    else hi = mid;
  }
  return lo;
}

__global__ __launch_bounds__(256) void k_pool(const float* __restrict__ gate,
                                              const int* __restrict__ batch,
                                              const float* __restrict__ h3,
                                              float* __restrict__ pooled, int N) {
  __shared__ float red[256];
  __shared__ int sb[2];
  __shared__ float sm[2];
  int g = blockIdx.x, tid = threadIdx.x;
  if (tid == 0) {
    sb[0] = lower_bound_i(batch, N, g);
    sb[1] = lower_bound_i(batch, N, g + 1);
  }
  __syncthreads();
  int lo = sb[0], hi = sb[1];
  // max
  float mx = -INFINITY;
  for (int i = lo + tid; i < hi; i += 256) mx = fmaxf(mx, gate[i]);
  red[tid] = mx;
  __syncthreads();
  for (int o = 128; o; o >>= 1) {
    if (tid < o) red[tid] = fmaxf(red[tid], red[tid + o]);
    __syncthreads();
  }
  if (tid == 0) sm[0] = red[0];
  __syncthreads();
  float m = sm[0];
  // sum of exp
  float s = 0.f;
  for (int i = lo + tid; i < hi; i += 256) s += expf(gate[i] - m);
  red[tid] = s;
  __syncthreads();
  for (int o = 128; o; o >>= 1) {
    if (tid < o) red[tid] += red[tid + o];
    __syncthreads();
  }
  if (tid == 0) sm[1] = (red[0] > 0.f) ? 1.0f / red[0] : 0.f;
  __syncthreads();
  float inv = sm[1];
  // weighted feature sum
  int d = tid & 63, sub = tid >> 6;
  float acc = 0.f;
  for (int i = lo + sub; i < hi; i += 4)
    acc += h3[(size_t)i * 64 + d] * expf(gate[i] - m);
  red[tid] = acc;
  __syncthreads();
  if (tid < 64)
    pooled[g * 64 + tid] =
        (red[tid] + red[tid + 64] + red[tid + 128] + red[tid + 192]) * inv;
}

// ---------------- head MLP (single block) ----------------
__global__ __launch_bounds__(256) void k_head(const float* __restrict__ pooled,
                                              const float* __restrict__ Wm1,
                                              const float* __restrict__ bm1,
                                              const float* __restrict__ Wm2,
                                              const float* __restrict__ bm2,
                                              float* __restrict__ out) {
  __shared__ float P[64 * 64];
  __shared__ float T[64 * 128];
  int tid = threadIdx.x;
  for (int i = tid; i < 4096; i += 256) P[i] = pooled[i];
  __syncthreads();
  for (int e = tid; e < 8192; e += 256) {
    int r = e >> 7, c = e & 127;
    float a = bm1[c];
    for (int k = 0; k < 64; ++k) a += P[r * 64 + k] * Wm1[k * 128 + c];
    T[e] = fmaxf(a, 0.f);
  }
  __syncthreads();
  for (int e = tid; e < 4096; e += 256) {
    int r = e >> 6, c = e & 63;
    float a = bm2[c];
    for (int k = 0; k < 128; ++k) a += T[r * 128 + k] * Wm2[k * 64 + c];
    out[e] = a;
  }
}

extern "C" void kernel_launch(void* const* d_in, const int* in_sizes, int n_in,
                              void* d_out, int out_size, void* d_ws,
                              size_t ws_size, hipStream_t stream) {
  const int N = NN, E = EE;
  const float* x = (const float*)d_in[0];
  const int* ei = (const int*)d_in[1];
  const int* batch = (const int*)d_in[2];
  const float* W1 = (const float*)d_in[3];
  const float* b1 = (const float*)d_in[4];
  const float* W2 = (const float*)d_in[5];
  const float* b2 = (const float*)d_in[6];
  const float* W3 = (const float*)d_in[7];
  const float* b3 = (const float*)d_in[8];
  const float* g1 = (const float*)d_in[9];
  const float* beta1 = (const float*)d_in[10];
  const float* g2 = (const float*)d_in[11];
  const float* beta2 = (const float*)d_in[12];
  const float* mean1 = (const float*)d_in[13];
  const float* var1 = (const float*)d_in[14];
  const float* mean2 = (const float*)d_in[15];
  const float* var2 = (const float*)d_in[16];
  const float* Wg1 = (const float*)d_in[17];
  const float* bg1 = (const float*)d_in[18];
  const float* Wg2 = (const float*)d_in[19];
  const float* bg2 = (const float*)d_in[20];
  const float* Wm1 = (const float*)d_in[21];
  const float* bm1 = (const float*)d_in[22];
  const float* Wm2 = (const float*)d_in[23];
  const float* bm2 = (const float*)d_in[24];
  float* out = (float*)d_out;

  const int* src = ei;
  const int* dst = ei + E;

  // workspace layout (all 16B aligned since N,E are multiples of 4)
  char* wsb = (char*)d_ws;
  size_t off = 0;
  auto alloc = [&](size_t elems) -> void* {
    void* p = wsb + off;
    off += elems * 4;
    return p;
  };
  int* cnt = (int*)alloc(N);
  int* rowstart = (int*)alloc(N + 4);
  int* cursor = (int*)alloc(N);
  int* eidx = (int*)alloc(E);
  float* dinv = (float*)alloc(N);
  float* gate = (float*)alloc(N);
  float* bufA = (float*)alloc((size_t)N * 128);
  float* bufB = (float*)alloc((size_t)N * 128);
  float* pooled = (float*)alloc(64 * 64);
  int* bsum = (int*)alloc(256);
  int* boff = (int*)alloc(256);
  (void)ws_size;
  (void)n_in;
  (void)in_sizes;
  (void)out_size;

  const int nscan = (N + SB - 1) / SB;  // 196 blocks

  // CSR build (once, reused for all 3 conv layers)
  hipMemsetAsync(cnt, 0, N * sizeof(int), stream);
  k_count<<<(E + 255) / 256, 256, 0, stream>>>(dst, cnt, E);
  k_scan1<<<nscan, SB, 0, stream>>>(cnt, dinv, bsum, N);
  k_scan2<<<1, 256, 0, stream>>>(bsum, boff, nscan, rowstart + N);
  k_scan3<<<nscan, SB, 0, stream>>>(cnt, boff, rowstart, cursor, N);
  k_fill<<<(E + 255) / 256, 256, 0, stream>>>(src, dst, cursor, eidx, E);

  const int gb = (N + 63) / 64;         // GEMM blocks
  const int ab = (N * 64 + 255) / 256;  // agg/gatedot blocks (wave per node)

  // Layer 1: h = x@W1 ; agg ; (BN1+relu fused into next gemm's load)
  k_gemm<128, 128, 0, 0><<<gb, 256, 0, stream>>>(
      x, W1, nullptr, nullptr, nullptr, nullptr, nullptr, bufA, N);
  k_agg<128><<<ab, 256, 0, stream>>>(bufA, rowstart, eidx, dinv, b1, bufB, N);

  // Layer 2
  k_gemm<128, 128, 1, 0><<<gb, 256, 0, stream>>>(
      bufB, W2, mean1, var1, g1, beta1, nullptr, bufA, N);
  k_agg<128><<<ab, 256, 0, stream>>>(bufA, rowstart, eidx, dinv, b2, bufB, N);

  // Layer 3 (output dim 64)
  k_gemm<128, 64, 1, 0><<<gb, 256, 0, stream>>>(
      bufB, W3, mean2, var2, g2, beta2, nullptr, bufA, N);
  k_agg<64><<<ab, 256, 0, stream>>>(bufA, rowstart, eidx, dinv, b3, bufB, N);
  // h3 = bufB (N x 64)

  // gate MLP: t1 = relu(h3@Wg1+bg1) -> bufA ; gate = t1@Wg2+bg2
  k_gemm<64, 128, 0, 1><<<gb, 256, 0, stream>>>(
      bufB, Wg1, nullptr, nullptr, nullptr, nullptr, bg1, bufA, N);
  k_gatedot<<<ab, 256, 0, stream>>>(bufA, Wg2, bg2, gate, N);

  // softmax pooling per graph
  k_pool<<<GG, 256, 0, stream>>>(gate, batch, bufB, pooled, N);

  // head MLP
  k_head<<<1, 256, 0, stream>>>(pooled, Wm1, bm1, Wm2, bm2, out);
}

// Round 3
// 934.027 us; speedup vs baseline: 1.3264x; 1.0822x over previous
//
#include <hip/hip_runtime.h>
#include <hip/hip_bf16.h>
#include <math.h>

#define NN 100000
#define EE 1000000
#define GG 64
#define BN_EPS 1e-5f
#define SB 512  // scan block size

// ---------------- degree count ----------------
__global__ __launch_bounds__(256) void k_count(const int* __restrict__ dst,
                                               int* __restrict__ cnt, int E) {
  int i = blockIdx.x * 256 + threadIdx.x;
  if (i < E) atomicAdd(&cnt[dst[i]], 1);
}

// ---------------- hierarchical scan ----------------
__global__ __launch_bounds__(SB) void k_scan1(const int* __restrict__ cnt,
                                              float* __restrict__ dinv,
                                              int* __restrict__ bsum, int N) {
  __shared__ int red[SB];
  int t = threadIdx.x;
  int i = blockIdx.x * SB + t;
  int v = (i < N) ? cnt[i] : 0;
  if (i < N) dinv[i] = rsqrtf(1.0f + (float)v);
  red[t] = v;
  __syncthreads();
  for (int o = SB / 2; o; o >>= 1) {
    if (t < o) red[t] += red[t + o];
    __syncthreads();
  }
  if (t == 0) bsum[blockIdx.x] = red[0];
}

__global__ __launch_bounds__(256) void k_scan2(const int* __restrict__ bsum,
                                               int* __restrict__ boff, int nb,
                                               int* __restrict__ total_out) {
  __shared__ int s[256];
  int t = threadIdx.x;
  int v = (t < nb) ? bsum[t] : 0;
  s[t] = v;
  __syncthreads();
  for (int o = 1; o < 256; o <<= 1) {
    int u = (t >= o) ? s[t - o] : 0;
    __syncthreads();
    s[t] += u;
    __syncthreads();
  }
  boff[t] = s[t] - v;  // exclusive
  if (t == 255) *total_out = s[255];
}

__global__ __launch_bounds__(SB) void k_scan3(const int* __restrict__ cnt,
                                              const int* __restrict__ boff,
                                              int* __restrict__ rowstart,
                                              int* __restrict__ cursor, int N) {
  __shared__ int s[SB];
  int t = threadIdx.x;
  int i = blockIdx.x * SB + t;
  int v = (i < N) ? cnt[i] : 0;
  s[t] = v;
  __syncthreads();
  for (int o = 1; o < SB; o <<= 1) {
    int u = (t >= o) ? s[t - o] : 0;
    __syncthreads();
    s[t] += u;
    __syncthreads();
  }
  int excl = s[t] - v + boff[blockIdx.x];
  if (i < N) {
    rowstart[i] = excl;
    cursor[i] = excl;
  }
}

__global__ __launch_bounds__(256) void k_fill(const int* __restrict__ src,
                                              const int* __restrict__ dst,
                                              int* __restrict__ cursor,
                                              int* __restrict__ eidx, int E) {
  int i = blockIdx.x * 256 + threadIdx.x;
  if (i < E) {
    int pos = atomicAdd(&cursor[dst[i]], 1);
    eidx[pos] = src[i];
  }
}

// ---------------- GEMM: Y[N,M] = f(X)[N,K] @ W[K,M] ----------------
// BN:   fused batchnorm+relu on X while staging to LDS
// DINV: epilogue scales row by dinv[row]  (GCN pre-scaling)
// GATE: epilogue computes gate[row] = relu(acc+obias) . Wg2 + bg2 (no Y write)
template <int K, int M, int BN, int DINV, int GATE>
__global__ __launch_bounds__(256) void k_gemm(
    const float* __restrict__ X, const float* __restrict__ W,
    const float* __restrict__ bn_mean, const float* __restrict__ bn_var,
    const float* __restrict__ bn_g, const float* __restrict__ bn_b,
    const float* __restrict__ dinv, const float* __restrict__ obias,
    const float* __restrict__ Wg2, const float* __restrict__ bg2,
    float* __restrict__ Y, float* __restrict__ gate, int nrows) {
  constexpr int ROWS = 64;
  constexpr int KC = (K > 64) ? 64 : K;  // K-chunk so LDS <= 64KB
  constexpr int CG = M / 4;              // column groups (4 cols each)
  constexpr int RG = 256 / CG;           // row groups
  constexpr int RPG = ROWS / RG;         // rows per thread
  __shared__ float Xs[ROWS * K];
  __shared__ float Ws[KC * M];
  const int tid = threadIdx.x;
  const int row0 = blockIdx.x * ROWS;

  // stage X tile (with optional fused BN+relu)
  constexpr int XV = ROWS * K / 4;
  for (int i = tid; i < XV; i += 256) {
    int flat = i * 4;
    int r = flat / K, k = flat % K;
    int row = row0 + r;
    float4 v = make_float4(0.f, 0.f, 0.f, 0.f);
    if (row < nrows) v = *(const float4*)(X + (size_t)row * K + k);
    if constexpr (BN) {
      float4 mn = *(const float4*)(bn_mean + k);
      float4 vr = *(const float4*)(bn_var + k);
      float4 gm = *(const float4*)(bn_g + k);
      float4 bt = *(const float4*)(bn_b + k);
      v.x = fmaxf((v.x - mn.x) * rsqrtf(vr.x + BN_EPS) * gm.x + bt.x, 0.f);
      v.y = fmaxf((v.y - mn.y) * rsqrtf(vr.y + BN_EPS) * gm.y + bt.y, 0.f);
      v.z = fmaxf((v.z - mn.z) * rsqrtf(vr.z + BN_EPS) * gm.z + bt.z, 0.f);
      v.w = fmaxf((v.w - mn.w) * rsqrtf(vr.w + BN_EPS) * gm.w + bt.w, 0.f);
    }
    *(float4*)(Xs + flat) = v;
  }

  const int c4 = (tid % CG) * 4;
  const int rg = tid / CG;
  float4 acc[RPG];
#pragma unroll
  for (int r = 0; r < RPG; ++r) acc[r] = make_float4(0.f, 0.f, 0.f, 0.f);

  for (int kc = 0; kc < K; kc += KC) {
    __syncthreads();
    for (int i = tid; i < KC * M / 4; i += 256)
      *(float4*)(Ws + i * 4) = *(const float4*)(W + (size_t)kc * M + i * 4);
    __syncthreads();
#pragma unroll 4
    for (int kk = 0; kk < KC; kk += 4) {
      float4 w0 = *(const float4*)(Ws + (kk + 0) * M + c4);
      float4 w1 = *(const float4*)(Ws + (kk + 1) * M + c4);
      float4 w2 = *(const float4*)(Ws + (kk + 2) * M + c4);
      float4 w3 = *(const float4*)(Ws + (kk + 3) * M + c4);
#pragma unroll
      for (int r = 0; r < RPG; ++r) {
        float4 xv = *(const float4*)(Xs + (rg * RPG + r) * K + kc + kk);
        acc[r].x += xv.x * w0.x + xv.y * w1.x + xv.z * w2.x + xv.w * w3.x;
        acc[r].y += xv.x * w0.y + xv.y * w1.y + xv.z * w2.y + xv.w * w3.y;
        acc[r].z += xv.x * w0.z + xv.y * w1.z + xv.z * w2.z + xv.w * w3.z;
        acc[r].w += xv.x * w0.w + xv.y * w1.w + xv.z * w2.w + xv.w * w3.w;
      }
    }
  }

  if constexpr (GATE) {
    // gate[row] = relu(acc + obias) . Wg2 + bg2   (no Y materialization)
    float4 ob = *(const float4*)(obias + c4);
    float4 gv = *(const float4*)(Wg2 + c4);
    float part[RPG];
#pragma unroll
    for (int r = 0; r < RPG; ++r) {
      float4 v = acc[r];
      v.x = fmaxf(v.x + ob.x, 0.f);
      v.y = fmaxf(v.y + ob.y, 0.f);
      v.z = fmaxf(v.z + ob.z, 0.f);
      v.w = fmaxf(v.w + ob.w, 0.f);
      part[r] = v.x * gv.x + v.y * gv.y + v.z * gv.z + v.w * gv.w;
    }
    // reduce across the 32 lanes of this row group (CG==32 -> one half-wave)
#pragma unroll
    for (int o = 16; o; o >>= 1) {
#pragma unroll
      for (int r = 0; r < RPG; ++r) part[r] += __shfl_xor(part[r], o, 64);
    }
    if ((tid & (CG - 1)) == 0) {
      float b2v = bg2[0];
#pragma unroll
      for (int r = 0; r < RPG; ++r) {
        int row = row0 + rg * RPG + r;
        if (row < nrows) gate[row] = part[r] + b2v;
      }
    }
  } else {
#pragma unroll
    for (int r = 0; r < RPG; ++r) {
      int row = row0 + rg * RPG + r;
      if (row < nrows) {
        float4 v = acc[r];
        if constexpr (DINV) {
          float dv = dinv[row];
          v.x *= dv;
          v.y *= dv;
          v.z *= dv;
          v.w *= dv;
        }
        *(float4*)(Y + (size_t)row * M + c4) = v;
      }
    }
  }
}

// ---------------- GCN aggregation (gather over CSR by dst) ----------------
// hp = h*dinv (pre-scaled in GEMM).  out[n] = dinv[n]*(sum hp[src] + hp[n]) + b
template <int M>
__global__ __launch_bounds__(256) void k_agg(const float* __restrict__ hp,
                                             const int* __restrict__ rowstart,
                                             const int* __restrict__ eidx,
                                             const float* __restrict__ dinv,
                                             const float* __restrict__ bias,
                                             float* __restrict__ out, int N) {
  int w = (blockIdx.x * 256 + threadIdx.x) >> 6;  // wave = node
  int l = threadIdx.x & 63;
  if (w >= N) return;
  float di = dinv[w];
  int lo = rowstart[w], hi = rowstart[w + 1];
  if constexpr (M == 128) {
    float2 acc = ((const float2*)(hp + (size_t)w * 128))[l];  // self term
    float2 bb = ((const float2*)bias)[l];
    int e = lo;
    for (; e + 4 <= hi; e += 4) {  // 4 gathers in flight per wave
      int s0 = eidx[e + 0], s1 = eidx[e + 1], s2 = eidx[e + 2], s3 = eidx[e + 3];
      float2 v0 = ((const float2*)(hp + (size_t)s0 * 128))[l];
      float2 v1 = ((const float2*)(hp + (size_t)s1 * 128))[l];
      float2 v2 = ((const float2*)(hp + (size_t)s2 * 128))[l];
      float2 v3 = ((const float2*)(hp + (size_t)s3 * 128))[l];
      acc.x += (v0.x + v1.x) + (v2.x + v3.x);
      acc.y += (v0.y + v1.y) + (v2.y + v3.y);
    }
    for (; e < hi; ++e) {
      int s = eidx[e];
      float2 v = ((const float2*)(hp + (size_t)s * 128))[l];
      acc.x += v.x;
      acc.y += v.y;
    }
    acc.x = acc.x * di + bb.x;
    acc.y = acc.y * di + bb.y;
    ((float2*)(out + (size_t)w * 128))[l] = acc;
  } else {
    float acc = hp[(size_t)w * 64 + l];
    float bb = bias[l];
    int e = lo;
    for (; e + 4 <= hi; e += 4) {
      int s0 = eidx[e + 0], s1 = eidx[e + 1], s2 = eidx[e + 2], s3 = eidx[e + 3];
      float v0 = hp[(size_t)s0 * 64 + l];
      float v1 = hp[(size_t)s1 * 64 + l];
      float v2 = hp[(size_t)s2 * 64 + l];
      float v3 = hp[(size_t)s3 * 64 + l];
      acc += (v0 + v1) + (v2 + v3);
    }
    for (; e < hi; ++e) acc += hp[(size_t)eidx[e] * 64 + l];
    out[(size_t)w * 64 + l] = acc * di + bb;
  }
}

// ---------------- softmax pooling (block per graph) ----------------
__device__ inline int lower_bound_i(const int* a, int n, int v) {
  int lo = 0, hi = n;
  while (lo < hi) {
    int mid = (lo + hi) >> 1;
    if (a[mid] < v) lo = mid + 1;
    else hi = mid;
  }
  return lo;
}

__global__ __launch_bounds__(256) void k_pool(const float* __restrict__ gate,
                                              const int* __restrict__ batch,
                                              const float* __restrict__ h3,
                                              float* __restrict__ pooled, int N) {
  __shared__ float red[256];
  __shared__ int sb[2];
  __shared__ float sm[2];
  int g = blockIdx.x, tid = threadIdx.x;
  if (tid == 0) {
    sb[0] = lower_bound_i(batch, N, g);
    sb[1] = lower_bound_i(batch, N, g + 1);
  }
  __syncthreads();
  int lo = sb[0], hi = sb[1];
  float mx = -INFINITY;
  for (int i = lo + tid; i < hi; i += 256) mx = fmaxf(mx, gate[i]);
  red[tid] = mx;
  __syncthreads();
  for (int o = 128; o; o >>= 1) {
    if (tid < o) red[tid] = fmaxf(red[tid], red[tid + o]);
    __syncthreads();
  }
  if (tid == 0) sm[0] = red[0];
  __syncthreads();
  float m = sm[0];
  float s = 0.f;
  for (int i = lo + tid; i < hi; i += 256) s += expf(gate[i] - m);
  red[tid] = s;
  __syncthreads();
  for (int o = 128; o; o >>= 1) {
    if (tid < o) red[tid] += red[tid + o];
    __syncthreads();
  }
  if (tid == 0) sm[1] = (red[0] > 0.f) ? 1.0f / red[0] : 0.f;
  __syncthreads();
  float inv = sm[1];
  int d = tid & 63, sub = tid >> 6;
  float acc = 0.f;
  for (int i = lo + sub; i < hi; i += 4)
    acc += h3[(size_t)i * 64 + d] * expf(gate[i] - m);
  red[tid] = acc;
  __syncthreads();
  if (tid < 64)
    pooled[g * 64 + tid] =
        (red[tid] + red[tid + 64] + red[tid + 128] + red[tid + 192]) * inv;
}

// ---------------- head MLP (single block) ----------------
__global__ __launch_bounds__(256) void k_head(const float* __restrict__ pooled,
                                              const float* __restrict__ Wm1,
                                              const float* __restrict__ bm1,
                                              const float* __restrict__ Wm2,
                                              const float* __restrict__ bm2,
                                              float* __restrict__ out) {
  __shared__ float P[64 * 64];
  __shared__ float T[64 * 128];
  int tid = threadIdx.x;
  for (int i = tid; i < 4096; i += 256) P[i] = pooled[i];
  __syncthreads();
  for (int e = tid; e < 8192; e += 256) {
    int r = e >> 7, c = e & 127;
    float a = bm1[c];
    for (int k = 0; k < 64; ++k) a += P[r * 64 + k] * Wm1[k * 128 + c];
    T[e] = fmaxf(a, 0.f);
  }
  __syncthreads();
  for (int e = tid; e < 4096; e += 256) {
    int r = e >> 6, c = e & 63;
    float a = bm2[c];
    for (int k = 0; k < 128; ++k) a += T[r * 128 + k] * Wm2[k * 64 + c];
    out[e] = a;
  }
}

extern "C" void kernel_launch(void* const* d_in, const int* in_sizes, int n_in,
                              void* d_out, int out_size, void* d_ws,
                              size_t ws_size, hipStream_t stream) {
  const int N = NN, E = EE;
  const float* x = (const float*)d_in[0];
  const int* ei = (const int*)d_in[1];
  const int* batch = (const int*)d_in[2];
  const float* W1 = (const float*)d_in[3];
  const float* b1 = (const float*)d_in[4];
  const float* W2 = (const float*)d_in[5];
  const float* b2 = (const float*)d_in[6];
  const float* W3 = (const float*)d_in[7];
  const float* b3 = (const float*)d_in[8];
  const float* g1 = (const float*)d_in[9];
  const float* beta1 = (const float*)d_in[10];
  const float* g2 = (const float*)d_in[11];
  const float* beta2 = (const float*)d_in[12];
  const float* mean1 = (const float*)d_in[13];
  const float* var1 = (const float*)d_in[14];
  const float* mean2 = (const float*)d_in[15];
  const float* var2 = (const float*)d_in[16];
  const float* Wg1 = (const float*)d_in[17];
  const float* bg1 = (const float*)d_in[18];
  const float* Wg2 = (const float*)d_in[19];
  const float* bg2 = (const float*)d_in[20];
  const float* Wm1 = (const float*)d_in[21];
  const float* bm1 = (const float*)d_in[22];
  const float* Wm2 = (const float*)d_in[23];
  const float* bm2 = (const float*)d_in[24];
  float* out = (float*)d_out;

  const int* src = ei;
  const int* dst = ei + E;

  char* wsb = (char*)d_ws;
  size_t off = 0;
  auto alloc = [&](size_t elems) -> void* {
    void* p = wsb + off;
    off += elems * 4;
    return p;
  };
  int* cnt = (int*)alloc(N);
  int* rowstart = (int*)alloc(N + 4);
  int* cursor = (int*)alloc(N);
  int* eidx = (int*)alloc(E);
  float* dinv = (float*)alloc(N);
  float* gate = (float*)alloc(N);
  float* bufA = (float*)alloc((size_t)N * 128);
  float* bufB = (float*)alloc((size_t)N * 128);
  float* pooled = (float*)alloc(64 * 64);
  int* bsum = (int*)alloc(256);
  int* boff = (int*)alloc(256);
  (void)ws_size;
  (void)n_in;
  (void)in_sizes;
  (void)out_size;

  const int nscan = (N + SB - 1) / SB;

  // CSR build (once, reused for all 3 conv layers)
  hipMemsetAsync(cnt, 0, N * sizeof(int), stream);
  k_count<<<(E + 255) / 256, 256, 0, stream>>>(dst, cnt, E);
  k_scan1<<<nscan, SB, 0, stream>>>(cnt, dinv, bsum, N);
  k_scan2<<<1, 256, 0, stream>>>(bsum, boff, nscan, rowstart + N);
  k_scan3<<<nscan, SB, 0, stream>>>(cnt, boff, rowstart, cursor, N);
  k_fill<<<(E + 255) / 256, 256, 0, stream>>>(src, dst, cursor, eidx, E);

  const int gb = (N + 63) / 64;         // GEMM blocks
  const int ab = (N * 64 + 255) / 256;  // agg blocks (wave per node)

  // Layer 1: h1' = (x@W1)*dinv ; agg
  k_gemm<128, 128, 0, 1, 0><<<gb, 256, 0, stream>>>(
      x, W1, nullptr, nullptr, nullptr, nullptr, dinv, nullptr, nullptr,
      nullptr, bufA, nullptr, N);
  k_agg<128><<<ab, 256, 0, stream>>>(bufA, rowstart, eidx, dinv, b1, bufB, N);

  // Layer 2 (BN1+relu fused into load)
  k_gemm<128, 128, 1, 1, 0><<<gb, 256, 0, stream>>>(
      bufB, W2, mean1, var1, g1, beta1, dinv, nullptr, nullptr, nullptr, bufA,
      nullptr, N);
  k_agg<128><<<ab, 256, 0, stream>>>(bufA, rowstart, eidx, dinv, b2, bufB, N);

  // Layer 3 (output dim 64)
  k_gemm<128, 64, 1, 1, 0><<<gb, 256, 0, stream>>>(
      bufB, W3, mean2, var2, g2, beta2, dinv, nullptr, nullptr, nullptr, bufA,
      nullptr, N);
  k_agg<64><<<ab, 256, 0, stream>>>(bufA, rowstart, eidx, dinv, b3, bufB, N);
  // h3 = bufB (N x 64)

  // gate = relu(h3@Wg1+bg1)@Wg2+bg2  (fused epilogue, no t1 materialization)
  k_gemm<64, 128, 0, 0, 1><<<gb, 256, 0, stream>>>(
      bufB, Wg1, nullptr, nullptr, nullptr, nullptr, nullptr, bg1, Wg2, bg2,
      nullptr, gate, N);

  // softmax pooling per graph
  k_pool<<<GG, 256, 0, stream>>>(gate, batch, bufB, pooled, N);

  // head MLP
  k_head<<<1, 256, 0, stream>>>(pooled, Wm1, bm1, Wm2, bm2, out);
}

// Round 4
// 849.319 us; speedup vs baseline: 1.4587x; 1.0997x over previous
//
#include <hip/hip_runtime.h>
#include <hip/hip_bf16.h>
#include <math.h>

#define NN 100000
#define EE 1000000
#define GG 64
#define BN_EPS 1e-5f
#define SB 512  // scan block size

typedef __attribute__((ext_vector_type(8))) short bf16x8;
typedef __attribute__((ext_vector_type(4))) float f32x4;

// float -> bf16 (RNE) and back, as raw shorts
__device__ inline short f2bf(float f) {
  unsigned u = __float_as_uint(f);
  u = u + 0x7fff + ((u >> 16) & 1);
  return (short)(u >> 16);
}
__device__ inline float bf2f(short h) {
  return __uint_as_float(((unsigned)(unsigned short)h) << 16);
}

// ---------------- degree count ----------------
__global__ __launch_bounds__(256) void k_count(const int* __restrict__ dst,
                                               int* __restrict__ cnt, int E) {
  int i = blockIdx.x * 256 + threadIdx.x;
  if (i < E) atomicAdd(&cnt[dst[i]], 1);
}

// ---------------- hierarchical scan ----------------
__global__ __launch_bounds__(SB) void k_scan1(const int* __restrict__ cnt,
                                              float* __restrict__ dinv,
                                              int* __restrict__ bsum, int N) {
  __shared__ int red[SB];
  int t = threadIdx.x;
  int i = blockIdx.x * SB + t;
  int v = (i < N) ? cnt[i] : 0;
  if (i < N) dinv[i] = rsqrtf(1.0f + (float)v);
  red[t] = v;
  __syncthreads();
  for (int o = SB / 2; o; o >>= 1) {
    if (t < o) red[t] += red[t + o];
    __syncthreads();
  }
  if (t == 0) bsum[blockIdx.x] = red[0];
}

__global__ __launch_bounds__(256) void k_scan2(const int* __restrict__ bsum,
                                               int* __restrict__ boff, int nb,
                                               int* __restrict__ total_out) {
  __shared__ int s[256];
  int t = threadIdx.x;
  int v = (t < nb) ? bsum[t] : 0;
  s[t] = v;
  __syncthreads();
  for (int o = 1; o < 256; o <<= 1) {
    int u = (t >= o) ? s[t - o] : 0;
    __syncthreads();
    s[t] += u;
    __syncthreads();
  }
  boff[t] = s[t] - v;  // exclusive
  if (t == 255) *total_out = s[255];
}

__global__ __launch_bounds__(SB) void k_scan3(const int* __restrict__ cnt,
                                              const int* __restrict__ boff,
                                              int* __restrict__ rowstart,
                                              int* __restrict__ cursor, int N) {
  __shared__ int s[SB];
  int t = threadIdx.x;
  int i = blockIdx.x * SB + t;
  int v = (i < N) ? cnt[i] : 0;
  s[t] = v;
  __syncthreads();
  for (int o = 1; o < SB; o <<= 1) {
    int u = (t >= o) ? s[t - o] : 0;
    __syncthreads();
    s[t] += u;
    __syncthreads();
  }
  int excl = s[t] - v + boff[blockIdx.x];
  if (i < N) {
    rowstart[i] = excl;
    cursor[i] = excl;
  }
}

__global__ __launch_bounds__(256) void k_fill(const int* __restrict__ src,
                                              const int* __restrict__ dst,
                                              int* __restrict__ cursor,
                                              int* __restrict__ eidx, int E) {
  int i = blockIdx.x * 256 + threadIdx.x;
  if (i < E) {
    int pos = atomicAdd(&cursor[dst[i]], 1);
    eidx[pos] = src[i];
  }
}

// ---------------- weight prep: transpose + split into bf16 hi/lo ----------------
// layout in wt (shorts):
//  [0]      Wt1hi 128x128   [16384] Wt1lo
//  [32768]  Wt2hi 128x128   [49152] Wt2lo
//  [65536]  Wt3hi  64x128(M=64,K=128 -> [n][k] = 64*128)   [73728] Wt3lo
//  [81920]  Wg1hi 128x64 ([n][k] = 128*64)                 [90112] Wg1lo
__global__ __launch_bounds__(256) void k_wsplit(const float* __restrict__ W1,
                                                const float* __restrict__ W2,
                                                const float* __restrict__ W3,
                                                const float* __restrict__ Wg1,
                                                short* __restrict__ wt) {
  int i = blockIdx.x * 256 + threadIdx.x;
  const float* W;
  short *hi, *lo;
  int K, M, idx;
  if (i < 16384) {
    W = W1; hi = wt; lo = wt + 16384; K = 128; M = 128; idx = i;
  } else if (i < 32768) {
    W = W2; hi = wt + 32768; lo = wt + 49152; K = 128; M = 128; idx = i - 16384;
  } else if (i < 40960) {
    W = W3; hi = wt + 65536; lo = wt + 73728; K = 128; M = 64; idx = i - 32768;
  } else {
    W = Wg1; hi = wt + 81920; lo = wt + 90112; K = 64; M = 128; idx = i - 40960;
  }
  int k = idx / M, n = idx % M;
  float w = W[idx];
  short h = f2bf(w);
  hi[n * K + k] = h;
  lo[n * K + k] = f2bf(w - bf2f(h));
}

// ---------------- BN prep: scale = g*rsqrt(var+eps), shift = beta - mean*scale
__global__ __launch_bounds__(256) void k_bnprep(
    const float* __restrict__ g1, const float* __restrict__ b1,
    const float* __restrict__ m1, const float* __restrict__ v1,
    const float* __restrict__ g2, const float* __restrict__ b2,
    const float* __restrict__ m2, const float* __restrict__ v2,
    float* __restrict__ s1, float* __restrict__ h1, float* __restrict__ s2,
    float* __restrict__ h2) {
  int i = threadIdx.x;
  if (i < 128) {
    float s = g1[i] * rsqrtf(v1[i] + BN_EPS);
    s1[i] = s;
    h1[i] = b1[i] - m1[i] * s;
  } else {
    int j = i - 128;
    float s = g2[j] * rsqrtf(v2[j] + BN_EPS);
    s2[j] = s;
    h2[j] = b2[j] - m2[j] * s;
  }
}

// ---------------- MFMA split-bf16 GEMM: Y[N,M] = f(X)[N,K] @ W[K,M] ----------------
// No LDS. 256 threads = 4 waves; each wave computes 16 rows x M cols.
// A-frags (hi+lo, all K/32 chunks) held in VGPRs; B-frags streamed from
// pre-transposed/split Wt (L2-broadcast). BN+relu fused into A load.
// DINV: scale output row by dinv[row]. GATE: gate[row]=relu(D+gbias).Wg2+bg2.
template <int K, int M, int BN, int DINV, int GATE>
__global__ __launch_bounds__(256, 4) void k_mgemm(
    const float* __restrict__ X, const short* __restrict__ Wthi,
    const short* __restrict__ Wtlo, const float* __restrict__ bns,
    const float* __restrict__ bnh, const float* __restrict__ dinv,
    const float* __restrict__ gbias, const float* __restrict__ Wg2v,
    const float* __restrict__ bg2v, float* __restrict__ Y,
    float* __restrict__ gate, int nrows) {
  constexpr int NC = K / 32;  // k chunks of 32
  constexpr int CT = M / 16;  // 16-col tiles
  const int lane = threadIdx.x & 63;
  const int wave = threadIdx.x >> 6;
  const int m16 = lane & 15;
  const int quad = lane >> 4;
  const int rowbase = blockIdx.x * 64 + wave * 16;
  const int arow = rowbase + m16;
  const bool rok = arow < nrows;

  // ---- load + split A fragments: A[m=m16][k = c*32 + quad*8 + j] ----
  bf16x8 ahi[NC], alo[NC];
#pragma unroll
  for (int c = 0; c < NC; ++c) {
    const int k0 = c * 32 + quad * 8;
    float4 v0 = make_float4(0.f, 0.f, 0.f, 0.f), v1 = v0;
    if (rok) {
      v0 = *(const float4*)(X + (size_t)arow * K + k0);
      v1 = *(const float4*)(X + (size_t)arow * K + k0 + 4);
    }
    float vv[8] = {v0.x, v0.y, v0.z, v0.w, v1.x, v1.y, v1.z, v1.w};
    if constexpr (BN) {
#pragma unroll
      for (int j = 0; j < 8; ++j)
        vv[j] = fmaxf(vv[j] * bns[k0 + j] + bnh[k0 + j], 0.f);
    }
#pragma unroll
    for (int j = 0; j < 8; ++j) {
      short h = f2bf(vv[j]);
      ahi[c][j] = h;
      alo[c][j] = f2bf(vv[j] - bf2f(h));
    }
  }

  float gp[4] = {0.f, 0.f, 0.f, 0.f};  // GATE partial dot
#pragma unroll
  for (int ct = 0; ct < CT; ++ct) {
    f32x4 acc = {0.f, 0.f, 0.f, 0.f};
    // B-frag: B[k = c*32 + quad*8 + j][n = ct*16 + m16], from Wt[n][k]
    const size_t wrow = (size_t)(ct * 16 + m16) * K + quad * 8;
#pragma unroll
    for (int c = 0; c < NC; ++c) {
      bf16x8 bhi = *(const bf16x8*)(Wthi + wrow + c * 32);
      bf16x8 blo = *(const bf16x8*)(Wtlo + wrow + c * 32);
      acc = __builtin_amdgcn_mfma_f32_16x16x32_bf16(ahi[c], bhi, acc, 0, 0, 0);
      acc = __builtin_amdgcn_mfma_f32_16x16x32_bf16(ahi[c], blo, acc, 0, 0, 0);
      acc = __builtin_amdgcn_mfma_f32_16x16x32_bf16(alo[c], bhi, acc, 0, 0, 0);
    }
    // D layout: row = quad*4 + r, col = m16
    if constexpr (GATE) {
      const int col = ct * 16 + m16;
      const float gb = gbias[col], wg = Wg2v[col];
#pragma unroll
      for (int r = 0; r < 4; ++r) gp[r] += fmaxf(acc[r] + gb, 0.f) * wg;
    } else {
#pragma unroll
      for (int r = 0; r < 4; ++r) {
        const int row = rowbase + quad * 4 + r;
        if (row < nrows) {
          float v = acc[r];
          if constexpr (DINV) v *= dinv[row];
          Y[(size_t)row * M + ct * 16 + m16] = v;
        }
      }
    }
  }
  if constexpr (GATE) {
    // reduce over the 16 column-lanes (masks < 16 stay in the 16-group)
#pragma unroll
    for (int o = 1; o < 16; o <<= 1) {
#pragma unroll
      for (int r = 0; r < 4; ++r) gp[r] += __shfl_xor(gp[r], o, 64);
    }
    if (m16 == 0) {
      const float b2 = bg2v[0];
#pragma unroll
      for (int r = 0; r < 4; ++r) {
        const int row = rowbase + quad * 4 + r;
        if (row < nrows) gate[row] = gp[r] + b2;
      }
    }
  }
}

// ---------------- GCN aggregation (gather over CSR by dst) ----------------
// hp = h*dinv (pre-scaled in GEMM).  out[n] = dinv[n]*(sum hp[src] + hp[n]) + b
template <int M>
__global__ __launch_bounds__(256) void k_agg(const float* __restrict__ hp,
                                             const int* __restrict__ rowstart,
                                             const int* __restrict__ eidx,
                                             const float* __restrict__ dinv,
                                             const float* __restrict__ bias,
                                             float* __restrict__ out, int N) {
  int w = (blockIdx.x * 256 + threadIdx.x) >> 6;  // wave = node
  int l = threadIdx.x & 63;
  if (w >= N) return;
  float di = dinv[w];
  int lo = rowstart[w], hi = rowstart[w + 1];
  if constexpr (M == 128) {
    float2 acc = ((const float2*)(hp + (size_t)w * 128))[l];  // self term
    float2 bb = ((const float2*)bias)[l];
    int e = lo;
    for (; e + 4 <= hi; e += 4) {  // 4 gathers in flight per wave
      int s0 = eidx[e + 0], s1 = eidx[e + 1], s2 = eidx[e + 2], s3 = eidx[e + 3];
      float2 v0 = ((const float2*)(hp + (size_t)s0 * 128))[l];
      float2 v1 = ((const float2*)(hp + (size_t)s1 * 128))[l];
      float2 v2 = ((const float2*)(hp + (size_t)s2 * 128))[l];
      float2 v3 = ((const float2*)(hp + (size_t)s3 * 128))[l];
      acc.x += (v0.x + v1.x) + (v2.x + v3.x);
      acc.y += (v0.y + v1.y) + (v2.y + v3.y);
    }
    for (; e < hi; ++e) {
      int s = eidx[e];
      float2 v = ((const float2*)(hp + (size_t)s * 128))[l];
      acc.x += v.x;
      acc.y += v.y;
    }
    acc.x = acc.x * di + bb.x;
    acc.y = acc.y * di + bb.y;
    ((float2*)(out + (size_t)w * 128))[l] = acc;
  } else {
    float acc = hp[(size_t)w * 64 + l];
    float bb = bias[l];
    int e = lo;
    for (; e + 4 <= hi; e += 4) {
      int s0 = eidx[e + 0], s1 = eidx[e + 1], s2 = eidx[e + 2], s3 = eidx[e + 3];
      float v0 = hp[(size_t)s0 * 64 + l];
      float v1 = hp[(size_t)s1 * 64 + l];
      float v2 = hp[(size_t)s2 * 64 + l];
      float v3 = hp[(size_t)s3 * 64 + l];
      acc += (v0 + v1) + (v2 + v3);
    }
    for (; e < hi; ++e) acc += hp[(size_t)eidx[e] * 64 + l];
    out[(size_t)w * 64 + l] = acc * di + bb;
  }
}

// ---------------- softmax pooling (block per graph) ----------------
__device__ inline int lower_bound_i(const int* a, int n, int v) {
  int lo = 0, hi = n;
  while (lo < hi) {
    int mid = (lo + hi) >> 1;
    if (a[mid] < v) lo = mid + 1;
    else hi = mid;
  }
  return lo;
}

__global__ __launch_bounds__(256) void k_pool(const float* __restrict__ gate,
                                              const int* __restrict__ batch,
                                              const float* __restrict__ h3,
                                              float* __restrict__ pooled, int N) {
  __shared__ float red[256];
  __shared__ int sb[2];
  __shared__ float sm[2];
  int g = blockIdx.x, tid = threadIdx.x;
  if (tid == 0) {
    sb[0] = lower_bound_i(batch, N, g);
    sb[1] = lower_bound_i(batch, N, g + 1);
  }
  __syncthreads();
  int lo = sb[0], hi = sb[1];
  float mx = -INFINITY;
  for (int i = lo + tid; i < hi; i += 256) mx = fmaxf(mx, gate[i]);
  red[tid] = mx;
  __syncthreads();
  for (int o = 128; o; o >>= 1) {
    if (tid < o) red[tid] = fmaxf(red[tid], red[tid + o]);
    __syncthreads();
  }
  if (tid == 0) sm[0] = red[0];
  __syncthreads();
  float m = sm[0];
  float s = 0.f;
  for (int i = lo + tid; i < hi; i += 256) s += expf(gate[i] - m);
  red[tid] = s;
  __syncthreads();
  for (int o = 128; o; o >>= 1) {
    if (tid < o) red[tid] += red[tid + o];
    __syncthreads();
  }
  if (tid == 0) sm[1] = (red[0] > 0.f) ? 1.0f / red[0] : 0.f;
  __syncthreads();
  float inv = sm[1];
  int d = tid & 63, sub = tid >> 6;
  float acc = 0.f;
  for (int i = lo + sub; i < hi; i += 4)
    acc += h3[(size_t)i * 64 + d] * expf(gate[i] - m);
  red[tid] = acc;
  __syncthreads();
  if (tid < 64)
    pooled[g * 64 + tid] =
        (red[tid] + red[tid + 64] + red[tid + 128] + red[tid + 192]) * inv;
}

// ---------------- head MLP (single block) ----------------
__global__ __launch_bounds__(256) void k_head(const float* __restrict__ pooled,
                                              const float* __restrict__ Wm1,
                                              const float* __restrict__ bm1,
                                              const float* __restrict__ Wm2,
                                              const float* __restrict__ bm2,
                                              float* __restrict__ out) {
  __shared__ float P[64 * 64];
  __shared__ float T[64 * 128];
  int tid = threadIdx.x;
  for (int i = tid; i < 4096; i += 256) P[i] = pooled[i];
  __syncthreads();
  for (int e = tid; e < 8192; e += 256) {
    int r = e >> 7, c = e & 127;
    float a = bm1[c];
    for (int k = 0; k < 64; ++k) a += P[r * 64 + k] * Wm1[k * 128 + c];
    T[e] = fmaxf(a, 0.f);
  }
  __syncthreads();
  for (int e = tid; e < 4096; e += 256) {
    int r = e >> 6, c = e & 63;
    float a = bm2[c];
    for (int k = 0; k < 128; ++k) a += T[r * 128 + k] * Wm2[k * 64 + c];
    out[e] = a;
  }
}

extern "C" void kernel_launch(void* const* d_in, const int* in_sizes, int n_in,
                              void* d_out, int out_size, void* d_ws,
                              size_t ws_size, hipStream_t stream) {
  const int N = NN, E = EE;
  const float* x = (const float*)d_in[0];
  const int* ei = (const int*)d_in[1];
  const int* batch = (const int*)d_in[2];
  const float* W1 = (const float*)d_in[3];
  const float* b1 = (const float*)d_in[4];
  const float* W2 = (const float*)d_in[5];
  const float* b2 = (const float*)d_in[6];
  const float* W3 = (const float*)d_in[7];
  const float* b3 = (const float*)d_in[8];
  const float* g1 = (const float*)d_in[9];
  const float* beta1 = (const float*)d_in[10];
  const float* g2 = (const float*)d_in[11];
  const float* beta2 = (const float*)d_in[12];
  const float* mean1 = (const float*)d_in[13];
  const float* var1 = (const float*)d_in[14];
  const float* mean2 = (const float*)d_in[15];
  const float* var2 = (const float*)d_in[16];
  const float* Wg1 = (const float*)d_in[17];
  const float* bg1 = (const float*)d_in[18];
  const float* Wg2 = (const float*)d_in[19];
  const float* bg2 = (const float*)d_in[20];
  const float* Wm1 = (const float*)d_in[21];
  const float* bm1 = (const float*)d_in[22];
  const float* Wm2 = (const float*)d_in[23];
  const float* bm2 = (const float*)d_in[24];
  float* out = (float*)d_out;

  const int* src = ei;
  const int* dst = ei + E;

  char* wsb = (char*)d_ws;
  size_t off = 0;
  auto alloc = [&](size_t elems) -> void* {
    void* p = wsb + off;
    off += elems * 4;
    return p;
  };
  int* cnt = (int*)alloc(N);
  int* rowstart = (int*)alloc(N + 4);
  int* cursor = (int*)alloc(N);
  int* eidx = (int*)alloc(E);
  float* dinv = (float*)alloc(N);
  float* gate = (float*)alloc(N);
  float* bufA = (float*)alloc((size_t)N * 128);
  float* bufB = (float*)alloc((size_t)N * 128);
  float* pooled = (float*)alloc(64 * 64);
  int* bsum = (int*)alloc(256);
  int* boff = (int*)alloc(256);
  short* wt = (short*)alloc(49152);  // 98304 shorts
  float* bn1s = (float*)alloc(128);
  float* bn1h = (float*)alloc(128);
  float* bn2s = (float*)alloc(128);
  float* bn2h = (float*)alloc(128);
  (void)ws_size;
  (void)n_in;
  (void)in_sizes;
  (void)out_size;

  const int nscan = (N + SB - 1) / SB;

  // CSR build (once, reused for all 3 conv layers)
  hipMemsetAsync(cnt, 0, N * sizeof(int), stream);
  k_count<<<(E + 255) / 256, 256, 0, stream>>>(dst, cnt, E);
  k_scan1<<<nscan, SB, 0, stream>>>(cnt, dinv, bsum, N);
  k_scan2<<<1, 256, 0, stream>>>(bsum, boff, nscan, rowstart + N);
  k_scan3<<<nscan, SB, 0, stream>>>(cnt, boff, rowstart, cursor, N);
  k_fill<<<(E + 255) / 256, 256, 0, stream>>>(src, dst, cursor, eidx, E);

  // weight/bn prep
  k_wsplit<<<192, 256, 0, stream>>>(W1, W2, W3, Wg1, wt);
  k_bnprep<<<1, 256, 0, stream>>>(g1, beta1, mean1, var1, g2, beta2, mean2,
                                  var2, bn1s, bn1h, bn2s, bn2h);

  const int gb = (N + 63) / 64;         // GEMM blocks (64 rows each)
  const int ab = (N * 64 + 255) / 256;  // agg blocks (wave per node)

  // Layer 1: h1' = (x@W1)*dinv ; agg
  k_mgemm<128, 128, 0, 1, 0><<<gb, 256, 0, stream>>>(
      x, wt, wt + 16384, nullptr, nullptr, dinv, nullptr, nullptr, nullptr,
      bufA, nullptr, N);
  k_agg<128><<<ab, 256, 0, stream>>>(bufA, rowstart, eidx, dinv, b1, bufB, N);

  // Layer 2 (BN1+relu fused into A load)
  k_mgemm<128, 128, 1, 1, 0><<<gb, 256, 0, stream>>>(
      bufB, wt + 32768, wt + 49152, bn1s, bn1h, dinv, nullptr, nullptr,
      nullptr, bufA, nullptr, N);
  k_agg<128><<<ab, 256, 0, stream>>>(bufA, rowstart, eidx, dinv, b2, bufB, N);

  // Layer 3 (M=64, BN2 fused)
  k_mgemm<128, 64, 1, 1, 0><<<gb, 256, 0, stream>>>(
      bufB, wt + 65536, wt + 73728, bn2s, bn2h, dinv, nullptr, nullptr,
      nullptr, bufA, nullptr, N);
  k_agg<64><<<ab, 256, 0, stream>>>(bufA, rowstart, eidx, dinv, b3, bufB, N);
  // h3 = bufB (N x 64)

  // gate = relu(h3@Wg1+bg1)@Wg2+bg2 (fused epilogue)
  k_mgemm<64, 128, 0, 0, 1><<<gb, 256, 0, stream>>>(
      bufB, wt + 81920, wt + 90112, nullptr, nullptr, nullptr, bg1, Wg2, bg2,
      nullptr, gate, N);

  // softmax pooling per graph
  k_pool<<<GG, 256, 0, stream>>>(gate, batch, bufB, pooled, N);

  // head MLP
  k_head<<<1, 256, 0, stream>>>(pooled, Wm1, bm1, Wm2, bm2, out);
}